// Round 1
// baseline (252.503 us; speedup 1.0000x reference)
//
#include <hip/hip_runtime.h>
#include <stdint.h>

// PixproLoss: out = -(sum_masked cos_sim / count_mask)
// cos_sim[b,p,q] = dot_c(base[b,c,p], moment[b,c,q]) / (||base[b,:,p]|| * ||moment[b,:,q]||)
// B=2048, C=256, P=49. Memory-bound: 225 MB mandatory reads -> ~36us floor.
// Strategy: bf16 MFMA (16x16x32) for the per-batch 49x49x256 matmul; one block per batch.

typedef __attribute__((ext_vector_type(8))) short short8;
typedef __attribute__((ext_vector_type(4))) float floatx4;

#define P 49
#define C 256
#define CP 12544           // C*P
#define NMASK 2401         // P*P
#define LDST 264           // LDS row stride in bf16 elems: 256 data + 8 pad (rows 16B-aligned, banks balanced)

__device__ __forceinline__ uint16_t f2bf_rne(float f) {
  union { float f; uint32_t u; } x; x.f = f;
  uint32_t u = x.u;
  u += 0x7FFFu + ((u >> 16) & 1u);   // round-to-nearest-even (inputs are finite gaussians, no NaN)
  return (uint16_t)(u >> 16);
}
__device__ __forceinline__ float bf2f(uint16_t h) {
  union { uint32_t u; float f; } x; x.u = ((uint32_t)h) << 16;
  return x.f;
}

__global__ __launch_bounds__(256) void pixpro_main(
    const float* __restrict__ base, const float* __restrict__ moment,
    const int* __restrict__ A, float* __restrict__ ws_num, float* __restrict__ ws_cnt)
{
  __shared__ uint16_t lb[P * LDST];   // base[b] transposed: [p][c], bf16
  __shared__ uint16_t lm[P * LDST];   // moment[b] transposed
  __shared__ float inv_nb[P], inv_nm[P];
  __shared__ float red[8];

  const int b    = blockIdx.x;
  const int tid  = threadIdx.x;
  const int lane = tid & 63;
  const int wv   = tid >> 6;

  const float* gb = base   + (size_t)b * CP;
  const float* gm = moment + (size_t)b * CP;

  // ---- Stage global [c][p] fp32 -> LDS [p][c] bf16 (transpose + convert) ----
  // task t: p = t%49, c-chunk = t/49 (8 c's). 8 strided-coalesced dword loads
  // (lanes sweep p => 196B segments), pack 8 bf16, one ds_write_b128 (bank-balanced).
  for (int arr = 0; arr < 2; ++arr) {
    const float* g = arr ? gm : gb;
    uint16_t*    l = arr ? lm : lb;
    for (int t = tid; t < 32 * P; t += 256) {
      int p  = t % P;
      int c0 = (t / P) * 8;
      float v[8];
      #pragma unroll
      for (int j = 0; j < 8; ++j) v[j] = g[(c0 + j) * P + p];
      union { uint16_t u[8]; short8 s; } pk;
      #pragma unroll
      for (int j = 0; j < 8; ++j) pk.u[j] = f2bf_rne(v[j]);
      *(short8*)&l[p * LDST + c0] = pk.s;
    }
  }
  __syncthreads();

  // ---- Norms (fp32 accumulation over the bf16-staged rows) ----
  if (wv < 2 && lane < P) {
    const uint16_t* row = (wv ? lm : lb) + lane * LDST;
    float s = 0.f;
    #pragma unroll 4
    for (int c8 = 0; c8 < 32; ++c8) {
      union { short8 s; uint16_t u[8]; } v;
      v.s = *(const short8*)&row[c8 * 8];
      #pragma unroll
      for (int j = 0; j < 8; ++j) { float f = bf2f(v.u[j]); s += f * f; }
    }
    float inv = 1.0f / fmaxf(sqrtf(s), 1e-6f);
    (wv ? inv_nm : inv_nb)[lane] = inv;
  }
  __syncthreads();

  // ---- MFMA: dots[p][q] = sum_c b[c][p] m[c][q]; wave wv owns p-tile wv, loops q-tiles ----
  // Tiles start at {0,16,32,33}: tile 3 covers rows 33..48; epilogue keeps only row 48 there.
  const int tbase[4] = {0, 16, 32, 33};
  const int pb   = tbase[wv];
  const int mrow = lane & 15;        // spatial index within 16-tile (m for A, n for B, col for D)
  const int kgrp = lane >> 4;        // k-group quad

  short8 afrag[8];
  #pragma unroll
  for (int kk = 0; kk < 8; ++kk)
    afrag[kk] = *(const short8*)&lb[(pb + mrow) * LDST + kk * 32 + kgrp * 8];

  float local_num = 0.f;
  int   local_cnt = 0;

  #pragma unroll
  for (int qt = 0; qt < 4; ++qt) {
    const int qb = tbase[qt];
    floatx4 acc = {0.f, 0.f, 0.f, 0.f};
    #pragma unroll
    for (int kk = 0; kk < 8; ++kk) {
      short8 bfrag = *(const short8*)&lm[(qb + mrow) * LDST + kk * 32 + kgrp * 8];
      acc = __builtin_amdgcn_mfma_f32_16x16x32_bf16(afrag[kk], bfrag, acc, 0, 0, 0);
    }
    const int  q      = qb + mrow;                    // <= 48 always
    const bool qvalid = (qt < 3) || (q == 48);
    const float inm   = inv_nm[q];
    #pragma unroll
    for (int r = 0; r < 4; ++r) {
      const int  p      = pb + kgrp * 4 + r;          // <= 48 always (D layout: row=(lane>>4)*4+r, col=lane&15)
      const bool pvalid = (wv < 3) || (p == 48);
      if (pvalid && qvalid) {
        int mval = A[(size_t)b * NMASK + p * P + q];
        if (mval != 0) {
          local_num += acc[r] * inv_nb[p] * inm;
          local_cnt += 1;
        }
      }
    }
  }

  // ---- Block reduction -> per-block partials (deterministic, no atomics) ----
  #pragma unroll
  for (int off = 32; off > 0; off >>= 1) {
    local_num += __shfl_down(local_num, off, 64);
    local_cnt += __shfl_down(local_cnt, off, 64);
  }
  if (lane == 0) { red[wv] = local_num; red[4 + wv] = (float)local_cnt; }
  __syncthreads();
  if (tid == 0) {
    ws_num[b] = red[0] + red[1] + red[2] + red[3];
    ws_cnt[b] = red[4] + red[5] + red[6] + red[7];
  }
}

__global__ __launch_bounds__(256) void pixpro_reduce(
    const float* __restrict__ ws_num, const float* __restrict__ ws_cnt,
    float* __restrict__ out)
{
  __shared__ float rn[4], rc[4];
  float n = 0.f, c = 0.f;
  for (int i = threadIdx.x; i < 2048; i += 256) { n += ws_num[i]; c += ws_cnt[i]; }
  #pragma unroll
  for (int off = 32; off > 0; off >>= 1) {
    n += __shfl_down(n, off, 64);
    c += __shfl_down(c, off, 64);
  }
  const int wv = threadIdx.x >> 6, lane = threadIdx.x & 63;
  if (lane == 0) { rn[wv] = n; rc[wv] = c; }
  __syncthreads();
  if (threadIdx.x == 0) {
    float N = rn[0] + rn[1] + rn[2] + rn[3];
    float D = rc[0] + rc[1] + rc[2] + rc[3];
    out[0] = -(N / D);
  }
}

extern "C" void kernel_launch(void* const* d_in, const int* in_sizes, int n_in,
                              void* d_out, int out_size, void* d_ws, size_t ws_size,
                              hipStream_t stream) {
  const float* base   = (const float*)d_in[0];
  const float* moment = (const float*)d_in[1];
  const int*   A      = (const int*)d_in[2];
  float* ws_num = (float*)d_ws;          // 2048 floats
  float* ws_cnt = ws_num + 2048;         // 2048 floats (16 KB total, fully rewritten every call)
  pixpro_main<<<2048, 256, 0, stream>>>(base, moment, A, ws_num, ws_cnt);
  pixpro_reduce<<<1, 256, 0, stream>>>(ws_num, ws_cnt, (float*)d_out);
}

// Round 2
// 235.372 us; speedup vs baseline: 1.0728x; 1.0728x over previous
//
#include <hip/hip_runtime.h>
#include <stdint.h>

// PixproLoss: out = -(sum_masked cos_sim / count_mask)
// cos[b,p,q] = dot_c(base[b,c,p], moment[b,c,q]) / (||b_p||*||m_q||), B=2048,C=256,P=49.
// R1 -> R2: latency-bound (occ 29%, all pipes idle). 512 thr/block (24 waves/CU @ 52KB LDS),
// hoisted staging loads (one vmcnt exposure), mask prefetch, register norms (no norms phase),
// barriers 3->2.

typedef __attribute__((ext_vector_type(8))) short short8;
typedef __attribute__((ext_vector_type(4))) float floatx4;

#define P 49
#define CP 12544           // C*P
#define NMASK 2401         // P*P
#define LDST 264           // LDS row stride (bf16): 256 data + 8 pad; 528B rows (16B-aligned, banks offset by 4)

__device__ __forceinline__ uint16_t f2bf_rne(float f) {
  union { float f; uint32_t u; } x; x.f = f;
  uint32_t u = x.u;
  u += 0x7FFFu + ((u >> 16) & 1u);   // RNE; inputs finite
  return (uint16_t)(u >> 16);
}
__device__ __forceinline__ float bf2f(uint16_t h) {
  union { uint32_t u; float f; } x; x.u = ((uint32_t)h) << 16;
  return x.f;
}

__global__ __launch_bounds__(512, 6) void pixpro_main(
    const float* __restrict__ base, const float* __restrict__ moment,
    const int* __restrict__ A, float* __restrict__ ws_num, float* __restrict__ ws_cnt)
{
  __shared__ uint16_t lb[P * LDST];   // base[b] as [p][c] bf16
  __shared__ uint16_t lm[P * LDST];   // moment[b] as [p][c] bf16
  __shared__ float red[16];

  const int b    = blockIdx.x;
  const int tid  = threadIdx.x;
  const int lane = tid & 63;
  const int wv   = tid >> 6;          // 0..7

  const float* gb = base   + (size_t)b * CP;
  const float* gm = moment + (size_t)b * CP;

  // ---- staging loads: 3 uniform rounds x 8, both arrays, all hoisted (48 loads in flight) ----
  float vb[3][8], vm[3][8];
  int pp[3], cc[3];
  #pragma unroll
  for (int k = 0; k < 3; ++k) {
    int t = tid + 512 * k;            // tasks 0..1535 (uniform); tail 1536..1567 below
    pp[k] = t % P;
    cc[k] = (t / P) * 8;
    const float* g0 = gb + cc[k] * P + pp[k];
    #pragma unroll
    for (int j = 0; j < 8; ++j) vb[k][j] = g0[j * P];
  }
  #pragma unroll
  for (int k = 0; k < 3; ++k) {
    const float* g1 = gm + cc[k] * P + pp[k];
    #pragma unroll
    for (int j = 0; j < 8; ++j) vm[k][j] = g1[j * P];
  }

  // ---- mask prefetch: 16 tile-pairs over 8 waves (2 q-tiles per wave), 8 ints/thread ----
  // tile bases {0,16,32,33}; tile 3 covers rows 33..48, epilogue keeps only row 48 there.
  const int mrow = lane & 15;
  const int kgrp = lane >> 4;
  const int pt   = wv & 3;
  const int qt0  = (wv >> 2) * 2;
  const int pb   = (pt == 3) ? 33 : 16 * pt;
  int mv[2][4];
  #pragma unroll
  for (int s = 0; s < 2; ++s) {
    int qt = qt0 + s;
    int qb = (qt == 3) ? 33 : 16 * qt;
    int q  = qb + mrow;                          // <= 48, always in-bounds
    const int* Ab = A + (size_t)b * NMASK + q;
    #pragma unroll
    for (int r = 0; r < 4; ++r) {
      int p = pb + kgrp * 4 + r;                 // <= 48
      mv[s][r] = Ab[p * P];
    }
  }

  // ---- pack fp32 -> bf16, transpose-write to LDS (ds_write_b128, bank-balanced) ----
  #pragma unroll
  for (int k = 0; k < 3; ++k) {
    union { uint16_t u[8]; short8 s8; } pk;
    #pragma unroll
    for (int j = 0; j < 8; ++j) pk.u[j] = f2bf_rne(vb[k][j]);
    *(short8*)&lb[pp[k] * LDST + cc[k]] = pk.s8;
    #pragma unroll
    for (int j = 0; j < 8; ++j) pk.u[j] = f2bf_rne(vm[k][j]);
    *(short8*)&lm[pp[k] * LDST + cc[k]] = pk.s8;
  }
  if (tid < 32) {                               // tail tasks 1536..1567
    int t = 1536 + tid;
    int p = t % P, c0 = (t / P) * 8;
    union { uint16_t u[8]; short8 s8; } pk;
    #pragma unroll
    for (int j = 0; j < 8; ++j) pk.u[j] = f2bf_rne(gb[(c0 + j) * P + p]);
    *(short8*)&lb[p * LDST + c0] = pk.s8;
    #pragma unroll
    for (int j = 0; j < 8; ++j) pk.u[j] = f2bf_rne(gm[(c0 + j) * P + p]);
    *(short8*)&lm[p * LDST + c0] = pk.s8;
  }
  __syncthreads();

  // ---- A-fragments + ||b_p|| from the fragments (no separate norms phase) ----
  short8 afrag[8];
  float sb = 0.f;
  #pragma unroll
  for (int kk = 0; kk < 8; ++kk) {
    afrag[kk] = *(const short8*)&lb[(pb + mrow) * LDST + kk * 32 + kgrp * 8];
    #pragma unroll
    for (int j = 0; j < 8; ++j) { float f = bf2f((uint16_t)afrag[kk][j]); sb = fmaf(f, f, sb); }
  }
  sb += __shfl_xor(sb, 16, 64);                  // merge the 4 kgrp slices of row pb+mrow
  sb += __shfl_xor(sb, 32, 64);
  const float inv_nb_own = 1.0f / fmaxf(sqrtf(sb), 1e-6f);
  float inv_nb_r[4];
  #pragma unroll
  for (int r = 0; r < 4; ++r) inv_nb_r[r] = __shfl(inv_nb_own, kgrp * 4 + r, 64);

  float local_num = 0.f;
  int   local_cnt = 0;

  #pragma unroll
  for (int s = 0; s < 2; ++s) {
    const int qt = qt0 + s;
    const int qb = (qt == 3) ? 33 : 16 * qt;
    floatx4 acc = {0.f, 0.f, 0.f, 0.f};
    float sm = 0.f;
    #pragma unroll
    for (int kk = 0; kk < 8; ++kk) {
      short8 bfrag = *(const short8*)&lm[(qb + mrow) * LDST + kk * 32 + kgrp * 8];
      #pragma unroll
      for (int j = 0; j < 8; ++j) { float f = bf2f((uint16_t)bfrag[j]); sm = fmaf(f, f, sm); }
      acc = __builtin_amdgcn_mfma_f32_16x16x32_bf16(afrag[kk], bfrag, acc, 0, 0, 0);
    }
    sm += __shfl_xor(sm, 16, 64);
    sm += __shfl_xor(sm, 32, 64);
    const float inv_nm_own = 1.0f / fmaxf(sqrtf(sm), 1e-6f);  // for q = qb+mrow (this lane's D column)
    const bool qvalid = (qt < 3) || (mrow == 15);
    #pragma unroll
    for (int r = 0; r < 4; ++r) {
      const bool pvalid = (pt < 3) || (kgrp * 4 + r == 15);   // D row = kgrp*4+r
      if (pvalid && qvalid && mv[s][r] != 0) {
        local_num += acc[r] * inv_nb_r[r] * inv_nm_own;
        local_cnt += 1;
      }
    }
  }

  // ---- block reduction (deterministic) ----
  #pragma unroll
  for (int off = 32; off > 0; off >>= 1) {
    local_num += __shfl_down(local_num, off, 64);
    local_cnt += __shfl_down(local_cnt, off, 64);
  }
  if (lane == 0) { red[wv] = local_num; red[8 + wv] = (float)local_cnt; }
  __syncthreads();
  if (tid == 0) {
    float n = 0.f, c = 0.f;
    #pragma unroll
    for (int i = 0; i < 8; ++i) { n += red[i]; c += red[8 + i]; }
    ws_num[b] = n; ws_cnt[b] = c;
  }
}

__global__ __launch_bounds__(256) void pixpro_reduce(
    const float* __restrict__ ws_num, const float* __restrict__ ws_cnt,
    float* __restrict__ out)
{
  __shared__ float rn[4], rc[4];
  float n = 0.f, c = 0.f;
  for (int i = threadIdx.x; i < 2048; i += 256) { n += ws_num[i]; c += ws_cnt[i]; }
  #pragma unroll
  for (int off = 32; off > 0; off >>= 1) {
    n += __shfl_down(n, off, 64);
    c += __shfl_down(c, off, 64);
  }
  const int wv = threadIdx.x >> 6, lane = threadIdx.x & 63;
  if (lane == 0) { rn[wv] = n; rc[wv] = c; }
  __syncthreads();
  if (threadIdx.x == 0) {
    float N = rn[0] + rn[1] + rn[2] + rn[3];
    float D = rc[0] + rc[1] + rc[2] + rc[3];
    out[0] = -(N / D);
  }
}

extern "C" void kernel_launch(void* const* d_in, const int* in_sizes, int n_in,
                              void* d_out, int out_size, void* d_ws, size_t ws_size,
                              hipStream_t stream) {
  const float* base   = (const float*)d_in[0];
  const float* moment = (const float*)d_in[1];
  const int*   A      = (const int*)d_in[2];
  float* ws_num = (float*)d_ws;          // 2048 floats
  float* ws_cnt = ws_num + 2048;         // 2048 floats
  pixpro_main<<<2048, 512, 0, stream>>>(base, moment, A, ws_num, ws_cnt);
  pixpro_reduce<<<1, 256, 0, stream>>>(ws_num, ws_cnt, (float*)d_out);
}

// Round 3
// 235.262 us; speedup vs baseline: 1.0733x; 1.0005x over previous
//
#include <hip/hip_runtime.h>
#include <hip/hip_bf16.h>
#include <stdint.h>

// PixproLoss: out = -(sum_masked cos_sim / count_mask), B=2048, C=256, P=49.
// R3 reformulation: m2[c,p] = sum_q (mask[p,q]*inv_nm[q]) * m[c,q]  (MFMA, M=256,N=49,K=49->64)
//                   num_b   = sum_p inv_nb[p] * sum_c b[c,p]*m2[c,p]   (fp32 VALU dot)
// -> no transpose, no big LDS staging, b read once in fp32, mask staged once as bf16*inv_nm.

typedef __attribute__((ext_vector_type(8))) short short8;
typedef __attribute__((ext_vector_type(4))) float floatx4;

#define P 49
#define CP 12544           // C*P
#define NMASK 2401         // P*P
#define MS_STRIDE 72       // maskS LDS row stride (bf16): 64 data + 8 pad (16B-aligned rows, bank-spread)

__device__ __forceinline__ short8 cvt8(float4 a, float4 b) {
  union { __hip_bfloat162 h2; short s2[2]; } t;
  short8 r;
  t.h2 = __float22bfloat162_rn(make_float2(a.x, a.y)); r[0] = t.s2[0]; r[1] = t.s2[1];
  t.h2 = __float22bfloat162_rn(make_float2(a.z, a.w)); r[2] = t.s2[0]; r[3] = t.s2[1];
  t.h2 = __float22bfloat162_rn(make_float2(b.x, b.y)); r[4] = t.s2[0]; r[5] = t.s2[1];
  t.h2 = __float22bfloat162_rn(make_float2(b.z, b.w)); r[6] = t.s2[0]; r[7] = t.s2[1];
  return r;
}

__global__ __launch_bounds__(512, 6) void pixpro_main(
    const float* __restrict__ base, const float* __restrict__ moment,
    const int* __restrict__ A, float* __restrict__ ws_num, float* __restrict__ ws_cnt)
{
  __shared__ __align__(16) uint16_t maskS[P * MS_STRIDE];      // mask*inv_nm, bf16: 7.1 KB
  __shared__ __align__(16) float normred[8 * 4 * 64];          // [w][h][q] partial nm^2: 8 KB
  __shared__ __align__(16) float inv_nm_s[64];
  __shared__ __align__(16) float SQred[8 * 4 * 16 * 2];        // [w][pt][mr][{S,Q}]: 4 KB
  __shared__ float cntred[8];

  const int b    = blockIdx.x;
  const int tid  = threadIdx.x;
  const int lane = tid & 63;
  const int wv   = tid >> 6;          // 0..7
  const int mrow = lane & 15;
  const int kgrp = (lane >> 4) & 3;

  const float* gb = base   + (size_t)b * CP;
  const float* gm = moment + (size_t)b * CP;
  const int*   gA = A      + (size_t)b * NMASK;

  // ---- P1: load m fragments fp32 straight from global (wave wv owns c-tiles 2wv, 2wv+1) ----
  // A-frag layout: lane -> A[m = mrow][k = kgrp*8 + j]; here m = c-within-tile, k = q.
  short8 afrag[2][2];                 // [cti][kt], bf16
  float s0[8], s1[8];                 // per-q nm^2 partials for q = kt*32 + kgrp*8 + j
  #pragma unroll
  for (int j = 0; j < 8; ++j) { s0[j] = 0.f; s1[j] = 0.f; }

  #pragma unroll
  for (int cti = 0; cti < 2; ++cti) {
    const int c = (2 * wv + cti) * 16 + mrow;
    const float* row = gm + c * P;
    // kt = 0: q = kgrp*8 .. +7 (all <= 31, valid)
    float4 a0 = *(const float4*)(row + kgrp * 8);
    float4 a1 = *(const float4*)(row + kgrp * 8 + 4);
    // kt = 1: q = 32 + kgrp*8 .. +7 ; valid q <= 48 only
    float4 b0, b1;
    if (kgrp < 2) {
      b0 = *(const float4*)(row + 32 + kgrp * 8);
      b1 = *(const float4*)(row + 32 + kgrp * 8 + 4);
    } else if (kgrp == 2) {
      b0 = make_float4(row[48], 0.f, 0.f, 0.f);   // q=48 only; idx <= 12543, always in-bounds
      b1 = make_float4(0.f, 0.f, 0.f, 0.f);
    } else {
      b0 = make_float4(0.f, 0.f, 0.f, 0.f);
      b1 = make_float4(0.f, 0.f, 0.f, 0.f);
    }
    s0[0] = fmaf(a0.x, a0.x, s0[0]); s0[1] = fmaf(a0.y, a0.y, s0[1]);
    s0[2] = fmaf(a0.z, a0.z, s0[2]); s0[3] = fmaf(a0.w, a0.w, s0[3]);
    s0[4] = fmaf(a1.x, a1.x, s0[4]); s0[5] = fmaf(a1.y, a1.y, s0[5]);
    s0[6] = fmaf(a1.z, a1.z, s0[6]); s0[7] = fmaf(a1.w, a1.w, s0[7]);
    s1[0] = fmaf(b0.x, b0.x, s1[0]); s1[1] = fmaf(b0.y, b0.y, s1[1]);
    s1[2] = fmaf(b0.z, b0.z, s1[2]); s1[3] = fmaf(b0.w, b0.w, s1[3]);
    s1[4] = fmaf(b1.x, b1.x, s1[4]); s1[5] = fmaf(b1.y, b1.y, s1[5]);
    s1[6] = fmaf(b1.z, b1.z, s1[6]); s1[7] = fmaf(b1.w, b1.w, s1[7]);
    afrag[cti][0] = cvt8(a0, a1);
    afrag[cti][1] = cvt8(b0, b1);
  }

  // ---- mask loads for B-build (issued before barriers to hide latency) ----
  const bool btask = tid < P * 8;     // 392 tasks: p = tid>>3, q-group = tid&7
  const int  bp    = tid >> 3;
  const int  bqg   = tid & 7;
  const int  bq0   = bqg * 8;
  int bmask[8];
  #pragma unroll
  for (int j = 0; j < 8; ++j) bmask[j] = 0;
  if (btask) {
    const int* Ar = gA + bp * P + bq0;
    if (bqg <= 5) {                   // q = bq0..bq0+7 <= 47, fully valid & in-bounds
      int4 u0 = *(const int4*)(Ar);
      int4 u1 = *(const int4*)(Ar + 4);
      bmask[0] = u0.x; bmask[1] = u0.y; bmask[2] = u0.z; bmask[3] = u0.w;
      bmask[4] = u1.x; bmask[5] = u1.y; bmask[6] = u1.z; bmask[7] = u1.w;
    } else if (bqg == 6) {            // only q=48 valid; scalar (avoids OOB at p=48)
      bmask[0] = Ar[0];
    }                                 // bqg == 7: all padding zeros
  }

  // ---- norm partial reduce: quad shuffle (sums mrow within groups of 4), store 4 holders/wave ----
  #pragma unroll
  for (int j = 0; j < 8; ++j) {
    s0[j] += __shfl_xor(s0[j], 1); s0[j] += __shfl_xor(s0[j], 2);
    s1[j] += __shfl_xor(s1[j], 1); s1[j] += __shfl_xor(s1[j], 2);
  }
  if ((lane & 3) == 0) {
    const int h = mrow >> 2;          // 0..3
    float* nb_ = &normred[(wv * 4 + h) * 64 + kgrp * 8];
    *(float4*)(nb_ + 0)  = make_float4(s0[0], s0[1], s0[2], s0[3]);
    *(float4*)(nb_ + 4)  = make_float4(s0[4], s0[5], s0[6], s0[7]);
    *(float4*)(nb_ + 32) = make_float4(s1[0], s1[1], s1[2], s1[3]);
    *(float4*)(nb_ + 36) = make_float4(s1[4], s1[5], s1[6], s1[7]);
  }
  __syncthreads();

  // ---- inv_nm (fp32 norms, matching reference) ----
  if (tid < 64) {
    float s = 0.f;
    #pragma unroll
    for (int wh = 0; wh < 32; ++wh) s += normred[wh * 64 + tid];
    inv_nm_s[tid] = 1.0f / fmaxf(sqrtf(s), 1e-6f);
  }
  __syncthreads();

  // ---- B-build: maskS[p][q] = mask[p][q] * inv_nm[q] (bf16), + mask count (each (p,q) once) ----
  int cntpart = 0;
  if (btask) {
    float4 i0 = *(const float4*)&inv_nm_s[bq0];
    float4 i1 = *(const float4*)&inv_nm_s[bq0 + 4];
    float4 f0, f1;
    f0.x = bmask[0] ? i0.x : 0.f; f0.y = bmask[1] ? i0.y : 0.f;
    f0.z = bmask[2] ? i0.z : 0.f; f0.w = bmask[3] ? i0.w : 0.f;
    f1.x = bmask[4] ? i1.x : 0.f; f1.y = bmask[5] ? i1.y : 0.f;
    f1.z = bmask[6] ? i1.z : 0.f; f1.w = bmask[7] ? i1.w : 0.f;
    #pragma unroll
    for (int j = 0; j < 8; ++j) cntpart += bmask[j];
    *(short8*)&maskS[bp * MS_STRIDE + bq0] = cvt8(f0, f1);
  }
  __syncthreads();

  // ---- MFMA: m2 tiles; B-frag: lane -> B[k = kgrp*8+j][n = mrow], read 16B from maskS row ----
  const int pbase[4] = {0, 16, 32, 33};   // tile 3 = rows 33..48 (dedup in epilogue)
  floatx4 acc[2][4];
  #pragma unroll
  for (int i = 0; i < 2; ++i)
    #pragma unroll
    for (int j = 0; j < 4; ++j) acc[i][j] = (floatx4){0.f, 0.f, 0.f, 0.f};

  #pragma unroll
  for (int kt = 0; kt < 2; ++kt) {
    short8 bfr[4];
    #pragma unroll
    for (int pt = 0; pt < 4; ++pt)
      bfr[pt] = *(const short8*)&maskS[(pbase[pt] + mrow) * MS_STRIDE + kt * 32 + kgrp * 8];
    #pragma unroll
    for (int cti = 0; cti < 2; ++cti)
      #pragma unroll
      for (int pt = 0; pt < 4; ++pt)
        acc[cti][pt] = __builtin_amdgcn_mfma_f32_16x16x32_bf16(afrag[cti][kt], bfr[pt], acc[cti][pt], 0, 0, 0);
  }

  // ---- Epilogue: S[p] = sum_c b[c,p]*m2[c,p], Q[p] = sum_c b[c,p]^2 (fp32, b read once) ----
  // D layout: col = lane&15 -> p-within-tile; row = kgrp*4+r -> c-within-tile.
  float S[4] = {0.f, 0.f, 0.f, 0.f}, Qn[4] = {0.f, 0.f, 0.f, 0.f};
  #pragma unroll
  for (int cti = 0; cti < 2; ++cti) {
    float bv[4][4];
    #pragma unroll
    for (int pt = 0; pt < 4; ++pt) {
      const int pd = pbase[pt] + mrow;
      const bool pv = (pt < 3) || (mrow == 15);   // dedup rows 33..47 of tile 3
      #pragma unroll
      for (int r = 0; r < 4; ++r) {
        const int c = (2 * wv + cti) * 16 + kgrp * 4 + r;
        float v = gb[c * P + pd];
        bv[pt][r] = pv ? v : 0.f;
      }
    }
    #pragma unroll
    for (int pt = 0; pt < 4; ++pt)
      #pragma unroll
      for (int r = 0; r < 4; ++r) {
        S[pt]  = fmaf(bv[pt][r], acc[cti][pt][r], S[pt]);
        Qn[pt] = fmaf(bv[pt][r], bv[pt][r], Qn[pt]);
      }
  }

  // reduce over kgrp (lane bits 4,5)
  #pragma unroll
  for (int pt = 0; pt < 4; ++pt) {
    S[pt]  += __shfl_xor(S[pt], 16);  S[pt]  += __shfl_xor(S[pt], 32);
    Qn[pt] += __shfl_xor(Qn[pt], 16); Qn[pt] += __shfl_xor(Qn[pt], 32);
  }
  float cntf = (float)cntpart;
  #pragma unroll
  for (int off = 32; off > 0; off >>= 1) cntf += __shfl_xor(cntf, off);

  if (lane < 16) {
    #pragma unroll
    for (int pt = 0; pt < 4; ++pt)
      *(float2*)&SQred[((wv * 4 + pt) * 16 + mrow) * 2] = make_float2(S[pt], Qn[pt]);
  }
  if (lane == 0) cntred[wv] = cntf;
  __syncthreads();

  // ---- final: num = sum_p S[p]/max(||b_p||,eps); one wave ----
  if (tid < 64) {
    float num = 0.f, cc = 0.f;
    if (tid < P) {
      const int pt = tid >> 4;                       // 48 -> 3
      const int mr = (pt == 3) ? 15 : (tid & 15);
      float Sp = 0.f, Qp = 0.f;
      #pragma unroll
      for (int w = 0; w < 8; ++w) {
        const int idx = ((w * 4 + pt) * 16 + mr) * 2;
        Sp += SQred[idx];
        Qp += SQred[idx + 1];
      }
      num = Sp * (1.0f / fmaxf(sqrtf(Qp), 1e-6f));
    }
    if (tid < 8) cc = cntred[tid];
    #pragma unroll
    for (int off = 32; off > 0; off >>= 1) {
      num += __shfl_xor(num, off);
      cc  += __shfl_xor(cc, off);
    }
    if (tid == 0) { ws_num[b] = num; ws_cnt[b] = cc; }
  }
}

__global__ __launch_bounds__(256) void pixpro_reduce(
    const float* __restrict__ ws_num, const float* __restrict__ ws_cnt,
    float* __restrict__ out)
{
  __shared__ float rn[4], rc[4];
  float n = 0.f, c = 0.f;
  for (int i = threadIdx.x; i < 2048; i += 256) { n += ws_num[i]; c += ws_cnt[i]; }
  #pragma unroll
  for (int off = 32; off > 0; off >>= 1) {
    n += __shfl_down(n, off, 64);
    c += __shfl_down(c, off, 64);
  }
  const int wv = threadIdx.x >> 6, lane = threadIdx.x & 63;
  if (lane == 0) { rn[wv] = n; rc[wv] = c; }
  __syncthreads();
  if (threadIdx.x == 0) {
    float N = rn[0] + rn[1] + rn[2] + rn[3];
    float D = rc[0] + rc[1] + rc[2] + rc[3];
    out[0] = -(N / D);
  }
}

extern "C" void kernel_launch(void* const* d_in, const int* in_sizes, int n_in,
                              void* d_out, int out_size, void* d_ws, size_t ws_size,
                              hipStream_t stream) {
  const float* base   = (const float*)d_in[0];
  const float* moment = (const float*)d_in[1];
  const int*   A      = (const int*)d_in[2];
  float* ws_num = (float*)d_ws;          // 2048 floats
  float* ws_cnt = ws_num + 2048;         // 2048 floats
  pixpro_main<<<2048, 512, 0, stream>>>(base, moment, A, ws_num, ws_cnt);
  pixpro_reduce<<<1, 256, 0, stream>>>(ws_num, ws_cnt, (float*)d_out);
}